// Round 2
// baseline (271.973 us; speedup 1.0000x reference)
//
#include <hip/hip_runtime.h>
#include <hip/hip_bf16.h>

// IrrepLinear: out[b, o*25+m] = sum_i x[b, i*25+m] * W[l(m), o, i]  (+bias at m=0)
// B=4096, IN=OUT=512, M=25, l(m)=floor(sqrt(m)).
// GEMM view: rows=(m,b_local) with row=m*16+b_local (16-row frags uniform in m),
// bf16 MFMA 16x16x32, fp32 accum. Memory-bound: ~425MB -> ~67us floor.

typedef __bf16 bf16x8 __attribute__((ext_vector_type(8)));
typedef float floatx4 __attribute__((ext_vector_type(4)));
typedef unsigned short ushort_t;
typedef unsigned short ushortx4 __attribute__((ext_vector_type(4)));

#define ROW_F 12800          // IN_F*M floats per batch row (also OUT_F*M)
#define SROW  72             // ushorts per LDS A row (128B data + 16B pad -> balanced b128 reads)
#define LDS_USH (400 * 72)   // 57600 B

__device__ __forceinline__ ushort_t f2bf(float f) {
    __hip_bfloat16 h = __float2bfloat16(f);   // RNE
    return __builtin_bit_cast(ushort_t, h);
}

// --- weight fp32 [5][512][512] -> bf16 in ws (same layout) ---
__global__ void cvt_w_kernel(const float* __restrict__ w, ushort_t* __restrict__ wb) {
    int i = (blockIdx.x * 256 + threadIdx.x) * 4;   // n = 1310720, grid 1280x256 exact
    floatx4 v = *reinterpret_cast<const floatx4*>(w + i);
    ushortx4 h;
    h.x = f2bf(v[0]); h.y = f2bf(v[1]); h.z = f2bf(v[2]); h.w = f2bf(v[3]);
    *reinterpret_cast<ushortx4*>(wb + i) = h;
}

__global__ __launch_bounds__(512, 2) void irrep_kernel(
        const float* __restrict__ x, const ushort_t* __restrict__ wb,
        const float* __restrict__ bias, float* __restrict__ out) {
    __shared__ __align__(16) ushort_t Asm[LDS_USH];

    const int tid  = threadIdx.x;
    const int lane = tid & 63;
    const int wv   = tid >> 6;      // 8 waves; each owns 16 output cols
    const int lr   = lane & 15;
    const int lh   = lane >> 4;

    // XCD swizzle: 1024 blocks, XCD x gets contiguous o-range -> the 4 col-tile
    // siblings of a b-tile are adjacent on one XCD (input re-reads hit L2).
    const int d     = blockIdx.x;
    const int o     = (d & 7) * 128 + (d >> 3);
    const int btile = o >> 2;       // 0..255
    const int ctile = o & 3;        // 0..3
    const int b0    = btile * 16;
    const int o0    = ctile * 128;
    const int ow    = o0 + wv * 16;

    constexpr int LOF[25] = {0,1,1,1,2,2,2,2,2,3,3,3,3,3,3,3,4,4,4,4,4,4,4,4,4};

    floatx4 acc[25];
#pragma unroll
    for (int m = 0; m < 25; ++m) acc[m] = (floatx4){0.f, 0.f, 0.f, 0.f};

    floatx4 vbuf[13];   // prefetch buffer: 6400 float4 per k-step / 512 threads

    auto prefetch = [&](int step) {
#pragma unroll
        for (int it = 0; it < 13; ++it) {
            int idx = tid + it * 512;
            if (idx < 6400) {
                int bb = idx / 400;          // batch row within tile
                int p  = idx - bb * 400;     // float4 within 1600-float chunk
                vbuf[it] = *reinterpret_cast<const floatx4*>(
                    x + (size_t)(b0 + bb) * ROW_F + (size_t)step * 1600 + p * 4);
            }
        }
    };

    auto scatter = [&]() {
#pragma unroll
        for (int it = 0; it < 13; ++it) {
            int idx = tid + it * 512;
            if (idx < 6400) {
                int bb = idx / 400;
                int p  = idx - bb * 400;
#pragma unroll
                for (int u = 0; u < 4; ++u) {
                    int q = p * 4 + u;       // 0..1599: q = i*25 + m
                    int i = q / 25;          // 0..63
                    int m = q - i * 25;
                    // XOR swizzle on the 16B granule spreads the 16-row-stride
                    // (bank-aliased) writes across 8 quad-slots.
                    Asm[(m * 16 + bb) * SROW + (i ^ ((m & 7) << 3))] = f2bf(vbuf[it][u]);
                }
            }
        }
    };

    prefetch(0);
#pragma unroll 1
    for (int step = 0; step < 8; ++step) {
        __syncthreads();                 // previous compute done with LDS
        scatter();                       // waits on vbuf vmcnt
        __syncthreads();
        if (step < 7) prefetch(step + 1); // in flight across compute (T14-lite)
        const int k0 = step * 64;
#pragma unroll
        for (int ks = 0; ks < 2; ++ks) {
            bf16x8 bfr[5];
#pragma unroll
            for (int l = 0; l < 5; ++l)
                bfr[l] = *reinterpret_cast<const bf16x8*>(
                    wb + (size_t)(l * 512 + ow + lr) * 512 + k0 + ks * 32 + lh * 8);
#pragma unroll
            for (int m = 0; m < 25; ++m) {
                const bf16x8 a = *reinterpret_cast<const bf16x8*>(
                    &Asm[(m * 16 + lr) * SROW + ((ks * 32 + lh * 8) ^ ((m & 7) << 3))]);
                acc[m] = __builtin_amdgcn_mfma_f32_16x16x32_bf16(a, bfr[LOF[m]], acc[m], 0, 0, 0);
            }
        }
    }

    // bias only on the m=0 (l=0 scalar) component
    {
        float bv = bias[ow + lr];
#pragma unroll
        for (int r = 0; r < 4; ++r) acc[0][r] += bv;
    }

    // Epilogue through LDS so global stores are contiguous float4 runs.
    // 4 passes; per pass, waves {2p,2p+1} dump their 16x(16cols x 25m) tile.
    float* ep = reinterpret_cast<float*>(Asm);
    constexpr int EPROW = 404;           // 400 data + 4 pad (breaks 4-way bank alias)
#pragma unroll 1
    for (int pass = 0; pass < 4; ++pass) {
        __syncthreads();                 // prior pass stores / k-loop reads done
        if ((wv >> 1) == pass) {
            const int half = wv & 1;
            float* epw = ep + half * (16 * EPROW);
#pragma unroll
            for (int m = 0; m < 25; ++m) {
#pragma unroll
                for (int r = 0; r < 4; ++r) {
                    int bl = lh * 4 + r;                 // batch row 0..15
                    epw[bl * EPROW + lr * 25 + m] = acc[m][r];
                }
            }
        }
        __syncthreads();
        // 2 halves * 16 rows * 400 floats = 3200 float4 stores, fully coalesced
        for (int idx = tid; idx < 3200; idx += 512) {
            int half = idx / 1600;
            int rem  = idx - half * 1600;
            int bl   = rem / 100;
            int q4   = rem - bl * 100;
            floatx4 v = *reinterpret_cast<const floatx4*>(
                &ep[half * (16 * EPROW) + bl * EPROW + q4 * 4]);
            *reinterpret_cast<floatx4*>(
                out + (size_t)(b0 + bl) * ROW_F
                    + (size_t)(o0 + (pass * 2 + half) * 16) * 25 + q4 * 4) = v;
        }
    }
}

extern "C" void kernel_launch(void* const* d_in, const int* in_sizes, int n_in,
                              void* d_out, int out_size, void* d_ws, size_t ws_size,
                              hipStream_t stream) {
    const float* x    = (const float*)d_in[0];
    const float* w    = (const float*)d_in[1];
    const float* bias = (const float*)d_in[2];
    float* outp       = (float*)d_out;
    ushort_t* wb      = (ushort_t*)d_ws;    // 2.62 MB bf16 weights

    cvt_w_kernel<<<1280, 256, 0, stream>>>(w, wb);
    irrep_kernel<<<1024, 512, 0, stream>>>(x, wb, bias, outp);
}